// Round 4
// baseline (781.767 us; speedup 1.0000x reference)
//
#include <hip/hip_runtime.h>

#define N_NODES 50000
#define N_EDGES 800000
#define N_GRAPHS 1024
#define IN_DIM 78
#define K1P 96            // IN_DIM padded to multiple of 32
#define HID 256
#define OUT_DIM 128

typedef unsigned short ushort_t;
typedef __attribute__((ext_vector_type(8))) short v8s;
typedef __attribute__((ext_vector_type(4))) float v4f;
typedef __attribute__((ext_vector_type(4))) unsigned int u4;
typedef __attribute__((ext_vector_type(2))) unsigned short us2;
typedef __attribute__((ext_vector_type(4))) unsigned short us4;
typedef __attribute__((ext_vector_type(8))) unsigned short us8;

__device__ __forceinline__ ushort_t f2bf(float f) {
    unsigned u = __float_as_uint(f);
    unsigned r = (u + 0x7fffu + ((u >> 16) & 1u)) >> 16;   // RNE
    return (ushort_t)r;
}
__device__ __forceinline__ float bf2f(ushort_t h) {
    return __uint_as_float((unsigned)h << 16);
}

// bijective XCD-chunked swizzle (m204): orig%8 = XCD round-robin position.
__device__ __forceinline__ int xcd_swizzle(int orig, int nwg) {
    int q = nwg >> 3, r = nwg & 7;
    int xcd = orig & 7, i = orig >> 3;
    return (xcd < r ? xcd * (q + 1) : r * (q + 1) + (xcd - r) * q) + i;
}

// ------------- fused weight transpose+pad+bf16 for ALL weights (1 launch) ------
__global__ __launch_bounds__(256)
void wt_all_kernel(const float* __restrict__ W1r, const float* __restrict__ W1o,
                   const float* __restrict__ W2r, const float* __restrict__ W2o,
                   const float* __restrict__ W3r, const float* __restrict__ W3o,
                   const float* __restrict__ Wfc, ushort_t* __restrict__ out)
{
    int i = blockIdx.x * 256 + threadIdx.x;
    if (i >= 901120) return;
    const float* W; int K, N, Kp, base;
    if      (i < 24576)  { W = W1r; K = IN_DIM; N = HID;     Kp = 96;  base = 0; }
    else if (i < 49152)  { W = W1o; K = IN_DIM; N = HID;     Kp = 96;  base = 24576; }
    else if (i < 180224) { W = W2r; K = HID;    N = 2 * HID; Kp = 256; base = 49152; }
    else if (i < 311296) { W = W2o; K = HID;    N = 2 * HID; Kp = 256; base = 180224; }
    else if (i < 573440) { W = W3r; K = 2*HID;  N = 2 * HID; Kp = 512; base = 311296; }
    else if (i < 835584) { W = W3o; K = 2*HID;  N = 2 * HID; Kp = 512; base = 573440; }
    else                 { W = Wfc; K = 2*HID;  N = OUT_DIM; Kp = 512; base = 835584; }
    int j = i - base;
    int n = j / Kp, k = j - n * Kp;
    float v = (k < K) ? W[(size_t)k * N + n] : 0.0f;
    out[i] = f2bf(v);
}

// ---------------- pad + cast activations: out[r][k<Kin?]=in, else 0 -----------
__global__ __launch_bounds__(256)
void pad_cast_kernel(const float* __restrict__ in, ushort_t* __restrict__ out,
                     int rows, int Kin, int Kout)
{
    int i = blockIdx.x * 256 + threadIdx.x;
    if (i >= rows * Kout) return;
    int r = i / Kout, k = i - r * Kout;
    out[i] = f2bf(k < Kin ? in[(size_t)r * Kin + k] : 0.0f);
}

// ---------------- CSR build ----------------------------------------------------
__global__ __launch_bounds__(256)
void hist_kernel(const int* __restrict__ dstI, int* __restrict__ deg, int nE)
{
    int e = blockIdx.x * 256 + threadIdx.x;
    if (e < nE) {
        int d = dstI[e];
        if ((unsigned)d < (unsigned)N_NODES) atomicAdd(&deg[d], 1);
    }
}

__global__ __launch_bounds__(1024)
void scan1_kernel(const int* __restrict__ deg, int* __restrict__ rowptr,
                  int* __restrict__ blocksum, int n)
{
    __shared__ int s[1024];
    int b = (int)blockIdx.x, t = (int)threadIdx.x;
    int i = b * 1024 + t;
    int v = (i < n) ? deg[i] : 0;
    s[t] = v;
    __syncthreads();
    for (int off = 1; off < 1024; off <<= 1) {
        int a = (t >= off) ? s[t - off] : 0;
        __syncthreads();
        s[t] += a;
        __syncthreads();
    }
    if (i < n) rowptr[i + 1] = s[t];      // block-local inclusive
    if (t == 1023) blocksum[b] = s[1023];
    if (b == 0 && t == 0) rowptr[0] = 0;
}

__global__ __launch_bounds__(64)
void scan2_kernel(int* __restrict__ blocksum, int nb)   // nb <= 64
{
    int t = (int)threadIdx.x;
    int v = (t < nb) ? blocksum[t] : 0;
    #pragma unroll
    for (int off = 1; off < 64; off <<= 1) {
        int a = __shfl_up(v, off, 64);
        if (t >= off) v += a;
    }
    if (t < nb) blocksum[t] = v;
}

__global__ __launch_bounds__(256)
void scan3_kernel(const int* __restrict__ blocksum, int* __restrict__ rowptr,
                  int* __restrict__ cursor, int n)
{
    int j = blockIdx.x * 256 + threadIdx.x;   // 0..n
    if (j > n) return;
    int v;
    if (j == 0) v = 0;
    else {
        int b = (j - 1) >> 10;
        v = rowptr[j] + (b >= 1 ? blocksum[b - 1] : 0);
    }
    rowptr[j] = v;
    if (j < n) cursor[j] = v;
}

__global__ __launch_bounds__(256)
void fill_kernel(const int* __restrict__ srcI, const int* __restrict__ dstI,
                 int* __restrict__ cursor, int* __restrict__ csr_src, int nE)
{
    int e = blockIdx.x * 256 + threadIdx.x;
    if (e < nE) {
        int d = dstI[e];
        int s = srcI[e];
        if ((unsigned)d < (unsigned)N_NODES && (unsigned)s < (unsigned)N_NODES) {
            int pos = atomicAdd(&cursor[d], 1);
            csr_src[pos] = s;
        }
    }
}

// ---------------- CSR aggregation, wave-per-node, 8-deep load pipeline ----------
template<int VPT> struct VecT;
template<> struct VecT<2> { using T = us2; };
template<> struct VecT<4> { using T = us4; };
template<> struct VecT<8> { using T = us8; };

template<int VPT>
__global__ __launch_bounds__(256)
void csr_agg_wave_kernel(const ushort_t* __restrict__ feat,
                         const int* __restrict__ rowptr,
                         const int* __restrict__ csr_src,
                         ushort_t* __restrict__ out, int Ds)
{
    using T = typename VecT<VPT>::T;
    const int wv   = (int)threadIdx.x >> 6;
    const int node = (int)blockIdx.x * 4 + wv;
    if (node >= N_NODES) return;
    const int lane = (int)threadIdx.x & 63;
    const int off0 = lane * VPT;
    const bool act = off0 < Ds;                    // Ds=96: lanes 48..63 idle
    const int off  = act ? off0 : (Ds - VPT);

    const int e0 = rowptr[node], e1 = rowptr[node + 1];
    float acc[VPT];
    #pragma unroll
    for (int i = 0; i < VPT; ++i) acc[i] = 0.0f;

    int e = e0;
    for (; e + 8 <= e1; e += 8) {
        T r[8];
        #pragma unroll
        for (int u = 0; u < 8; ++u) {
            int s = csr_src[e + u];
            r[u] = *(const T*)(feat + (size_t)s * Ds + off);
        }
        #pragma unroll
        for (int u = 0; u < 8; ++u)
            #pragma unroll
            for (int i = 0; i < VPT; ++i) acc[i] += bf2f(r[u][i]);
    }
    for (; e + 4 <= e1; e += 4) {
        T r[4];
        #pragma unroll
        for (int u = 0; u < 4; ++u) {
            int s = csr_src[e + u];
            r[u] = *(const T*)(feat + (size_t)s * Ds + off);
        }
        #pragma unroll
        for (int u = 0; u < 4; ++u)
            #pragma unroll
            for (int i = 0; i < VPT; ++i) acc[i] += bf2f(r[u][i]);
    }
    for (; e < e1; ++e) {
        int s = csr_src[e];
        T r = *(const T*)(feat + (size_t)s * Ds + off);
        #pragma unroll
        for (int i = 0; i < VPT; ++i) acc[i] += bf2f(r[i]);
    }

    if (act) {
        T o;
        #pragma unroll
        for (int i = 0; i < VPT; ++i) o[i] = f2bf(acc[i]);
        *(T*)(out + (size_t)node * Ds + off0) = o;
    }
}

// ---------------- bf16 MFMA GEMM, direct-fragment loads (no LDS main loop) ------
// out = relu?( A1@W1t^T + A2@W2t^T + bias ),  A*: bf16 [M][K], W*t: bf16 [Fo][K]
// 128x128 tile, BK=32, 4 waves 2x2. Both operands are row-major in fragment
// order: lane l's fragment for tile t is the contiguous 16B at
// row(bm+t*16+(l&15)), cols k0+(l>>4)*8. So frags load DIRECTLY from global
// (L2-resident), register-double-buffered, unrolled-by-2 (static indexing).
// No barriers, no LDS in main loop => no vmcnt(0) drain, no LDS-pipe pressure.
// bf16 out via LDS re-stage (full 16B/lane stores). K mult of 32, nsteps even,
// Fo mult of 128. M-tail: A rows clamped (garbage rows never stored).
__global__ __launch_bounds__(256, 3)
void mfma_gemm_kernel(const ushort_t* __restrict__ A1,
                      const ushort_t* __restrict__ A2,
                      const ushort_t* __restrict__ W1t,
                      const ushort_t* __restrict__ W2t,
                      const float* __restrict__ bias,
                      ushort_t* __restrict__ outp,
                      int M, int K, int Fo, int relu)
{
    __shared__ __align__(16) ushort_t smem[17408];   // epilogue re-stage only
    const int tid = (int)threadIdx.x;
    const int l   = tid & 63;
    const int w   = tid >> 6;
    const int q   = l >> 4;
    const int r15 = l & 15;
    const int wm  = w >> 1, wn = w & 1;

    const int wg = xcd_swizzle((int)blockIdx.x, (int)gridDim.x);
    const int nx = Fo >> 7;
    const int bx = wg % nx;
    const int by = wg / nx;
    const int bm = by * 128;
    const int bn = bx * 128;

    const int s1 = K >> 5;                       // steps per pass
    const int nsteps = A2 ? (2 * s1) : s1;       // always even here

    // per-lane global offsets of this wave's own fragments
    int aOffD[4], bOffD[4];
    #pragma unroll
    for (int mt = 0; mt < 4; ++mt) {
        int r = bm + (wm * 4 + mt) * 16 + r15;
        if (r >= M) r = M - 1;                   // clamp; rows >= M never stored
        aOffD[mt] = r * K + q * 8;
    }
    #pragma unroll
    for (int nt = 0; nt < 4; ++nt) {
        int c = bn + (wn * 4 + nt) * 16 + r15;   // Fo multiple of 128 => in range
        bOffD[nt] = c * K + q * 8;
    }

    v4f acc[4][4];
    #pragma unroll
    for (int mt = 0; mt < 4; ++mt)
        #pragma unroll
        for (int nt = 0; nt < 4; ++nt)
            acc[mt][nt] = (v4f){0.0f, 0.0f, 0.0f, 0.0f};

    v8s a0[4], b0[4], a1[4], b1[4];
    auto loadf = [&](int step, v8s* fa, v8s* fb) {
        const ushort_t* A  = (step >= s1) ? A2  : A1;
        const ushort_t* Bt = (step >= s1) ? W2t : W1t;
        const int k0 = ((step >= s1) ? (step - s1) : step) << 5;
        #pragma unroll
        for (int mt = 0; mt < 4; ++mt)
            fa[mt] = *(const v8s*)(A + aOffD[mt] + k0);
        #pragma unroll
        for (int nt = 0; nt < 4; ++nt)
            fb[nt] = *(const v8s*)(Bt + bOffD[nt] + k0);
    };
    auto mma = [&](v8s* fa, v8s* fb) {
        #pragma unroll
        for (int mt = 0; mt < 4; ++mt)
            #pragma unroll
            for (int nt = 0; nt < 4; ++nt)
                acc[mt][nt] = __builtin_amdgcn_mfma_f32_16x16x32_bf16(
                    fa[mt], fb[nt], acc[mt][nt], 0, 0, 0);
    };

    loadf(0, a0, b0);
    for (int step = 0; step < nsteps; step += 2) {
        loadf(step + 1, a1, b1);                 // in flight over mma(a0)
        mma(a0, b0);
        if (step + 2 < nsteps) loadf(step + 2, a0, b0);   // in flight over mma(a1)
        mma(a1, b1);
    }

    // epilogue: C/D map col=lane&15, row=q*4+reg; LDS re-stage, 16B/lane stores
    #pragma unroll
    for (int nt = 0; nt < 4; ++nt) {
        int col = wn * 64 + nt * 16 + r15;
        float bb = bias[bn + col];
        #pragma unroll
        for (int mt = 0; mt < 4; ++mt) {
            int row0 = wm * 64 + mt * 16 + q * 4;
            #pragma unroll
            for (int p = 0; p < 4; ++p) {
                float v = acc[mt][nt][p] + bb;
                if (relu) v = fmaxf(v, 0.0f);
                smem[(size_t)(row0 + p) * 136 + col] = f2bf(v);
            }
        }
    }
    __syncthreads();
    #pragma unroll
    for (int pass = 0; pass < 8; ++pass) {
        int row = pass * 16 + (tid >> 4);
        int gr  = bm + row;
        if (gr < M) {
            u4 v = *(const u4*)(smem + (size_t)row * 136 + (tid & 15) * 8);
            *(u4*)(outp + (size_t)gr * Fo + bn + (tid & 15) * 8) = v;
        }
    }
}

// ---------------- fc GEMM (Fo=128) + fused LayerNorm + ReLU + pool --------------
// Direct-fragment main loop (as above, single A). Each block owns 128 complete
// output rows, so LN is block-local. Pooling: block-local segmented reduction
// over sorted batch runs, one atomicAdd per (run x column).
__global__ __launch_bounds__(256, 3)
void mfma_fc_ln_kernel(const ushort_t* __restrict__ A,
                       const ushort_t* __restrict__ Wt,
                       const float* __restrict__ bias,
                       const float* __restrict__ gamma,
                       const float* __restrict__ beta,
                       const int* __restrict__ batch,
                       float* __restrict__ x_atom,
                       float* __restrict__ pooled,
                       int M, int K)
{
    __shared__ __align__(16) float sf[64 * 132];     // epilogue only
    const int tid = (int)threadIdx.x;
    const int l   = tid & 63;
    const int w   = tid >> 6;
    const int q   = l >> 4;
    const int r15 = l & 15;
    const int wm  = w >> 1, wn = w & 1;
    const int bm  = (int)blockIdx.x * 128;
    const int nsteps = K >> 5;                       // 16, even

    int aOffD[4], bOffD[4];
    #pragma unroll
    for (int mt = 0; mt < 4; ++mt) {
        int r = bm + (wm * 4 + mt) * 16 + r15;
        if (r >= M) r = M - 1;
        aOffD[mt] = r * K + q * 8;
    }
    #pragma unroll
    for (int nt = 0; nt < 4; ++nt) {
        int c = wn * 64 + nt * 16 + r15;             // Fo=128 cols exactly
        bOffD[nt] = c * K + q * 8;
    }

    v4f acc[4][4];
    #pragma unroll
    for (int mt = 0; mt < 4; ++mt)
        #pragma unroll
        for (int nt = 0; nt < 4; ++nt)
            acc[mt][nt] = (v4f){0.0f, 0.0f, 0.0f, 0.0f};

    v8s a0[4], b0[4], a1[4], b1[4];
    auto loadf = [&](int step, v8s* fa, v8s* fb) {
        const int k0 = step << 5;
        #pragma unroll
        for (int mt = 0; mt < 4; ++mt)
            fa[mt] = *(const v8s*)(A + aOffD[mt] + k0);
        #pragma unroll
        for (int nt = 0; nt < 4; ++nt)
            fb[nt] = *(const v8s*)(Wt + bOffD[nt] + k0);
    };
    auto mma = [&](v8s* fa, v8s* fb) {
        #pragma unroll
        for (int mt = 0; mt < 4; ++mt)
            #pragma unroll
            for (int nt = 0; nt < 4; ++nt)
                acc[mt][nt] = __builtin_amdgcn_mfma_f32_16x16x32_bf16(
                    fa[mt], fb[nt], acc[mt][nt], 0, 0, 0);
    };

    loadf(0, a0, b0);
    for (int step = 0; step < nsteps; step += 2) {
        loadf(step + 1, a1, b1);
        mma(a0, b0);
        if (step + 2 < nsteps) loadf(step + 2, a0, b0);
        mma(a1, b1);
    }

    // fused LN epilogue: two halves of 64 rows through LDS (64x132 f32)
    const int lrow = tid >> 2;            // 0..63
    const int c0   = (tid & 3) * 32;
    float pacc = 0.0f;                    // per-column running pool sum (tid<128)
    int   pcur = -1;                      // current graph id of the run
    #pragma unroll
    for (int half = 0; half < 2; ++half) {
        __syncthreads();                  // pooling reads done before overwrite
        if (wm == half) {
            #pragma unroll
            for (int nt = 0; nt < 4; ++nt) {
                int col = wn * 64 + nt * 16 + r15;
                float bb = bias[col];
                #pragma unroll
                for (int mt = 0; mt < 4; ++mt) {
                    int row0 = mt * 16 + q * 4;
                    #pragma unroll
                    for (int p = 0; p < 4; ++p)
                        sf[(size_t)(row0 + p) * 132 + col] = acc[mt][nt][p] + bb;
                }
            }
        }
        __syncthreads();
        int gr = bm + half * 64 + lrow;
        float* rowp = sf + (size_t)lrow * 132 + c0;
        float s = 0.0f;
        #pragma unroll
        for (int j = 0; j < 32; j += 4) {
            v4f t = *(const v4f*)(rowp + j);
            s += t[0] + t[1] + t[2] + t[3];
        }
        s += __shfl_xor(s, 1, 64);
        s += __shfl_xor(s, 2, 64);
        float mean = s * (1.0f / 128.0f);
        float s2 = 0.0f;
        #pragma unroll
        for (int j = 0; j < 32; j += 4) {
            v4f t = *(const v4f*)(rowp + j);
            #pragma unroll
            for (int k = 0; k < 4; ++k) { float d = t[k] - mean; s2 += d * d; }
        }
        s2 += __shfl_xor(s2, 1, 64);
        s2 += __shfl_xor(s2, 2, 64);
        float rstd = rsqrtf(s2 * (1.0f / 128.0f) + 1e-5f);
        bool rok = gr < M;
        #pragma unroll
        for (int j = 0; j < 32; j += 4) {
            v4f t  = *(const v4f*)(rowp + j);
            v4f g  = *(const v4f*)(gamma + c0 + j);
            v4f bt = *(const v4f*)(beta + c0 + j);
            v4f y;
            #pragma unroll
            for (int k = 0; k < 4; ++k)
                y[k] = fmaxf((t[k] - mean) * rstd * g[k] + bt[k], 0.0f);
            if (rok) *(v4f*)(x_atom + (size_t)gr * 128 + c0 + j) = y;
            *(v4f*)(rowp + j) = y;        // y back into LDS for pooling
        }
        __syncthreads();                  // y visible to pooling readers
        if (tid < 128) {                  // thread t owns column t
            for (int r = 0; r < 64; ++r) {
                int grr = bm + half * 64 + r;
                if (grr >= M) break;
                int b = batch[grr];
                if (b != pcur) {
                    if (pcur >= 0 && pacc != 0.0f)
                        atomicAdd(pooled + (size_t)pcur * 128 + tid, pacc);
                    pcur = b; pacc = 0.0f;
                }
                pacc += sf[(size_t)r * 132 + tid];
            }
        }
    }
    if (tid < 128 && pcur >= 0)
        atomicAdd(pooled + (size_t)pcur * 128 + tid, pacc);
}

extern "C" void kernel_launch(void* const* d_in, const int* in_sizes, int n_in,
                              void* d_out, int out_size, void* d_ws, size_t ws_size,
                              hipStream_t stream)
{
    const float* x     = (const float*)d_in[0];
    const int*   ei    = (const int*)d_in[1];
    const int*   batch = (const int*)d_in[2];
    const float* W1r   = (const float*)d_in[3];
    const float* b1    = (const float*)d_in[4];
    const float* W1o   = (const float*)d_in[5];
    const float* W2r   = (const float*)d_in[6];
    const float* b2    = (const float*)d_in[7];
    const float* W2o   = (const float*)d_in[8];
    const float* W3r   = (const float*)d_in[9];
    const float* b3    = (const float*)d_in[10];
    const float* W3o   = (const float*)d_in[11];
    const float* Wfc   = (const float*)d_in[12];
    const float* bfc   = (const float*)d_in[13];
    const float* lng   = (const float*)d_in[14];
    const float* lnb   = (const float*)d_in[15];

    const size_t WS_NEED = 204800000;
    if (ws_size < WS_NEED) {
        hipMemsetAsync(d_out, 0, (size_t)out_size * sizeof(float), stream);
        return;
    }

    char* ws = (char*)d_ws;
    ushort_t* xb   = (ushort_t*)(ws + 0);            // 50000x96 bf16
    ushort_t* h1   = (ushort_t*)(ws + 9600000);      // 50000x256 bf16
    ushort_t* aggr = (ushort_t*)(ws + 35200000);     // up to 50000x512 bf16
    ushort_t* h2   = (ushort_t*)(ws + 86400000);     // 50000x512 bf16
    ushort_t* h3   = (ushort_t*)(ws + 137600000);    // 50000x512 bf16
    int* deg    = (int*)(ws + 188800000);            // 50000
    int* rowptr = (int*)(ws + 189000000);            // 50001
    int* cursor = (int*)(ws + 189200128);            // 50000
    int* csrsrc = (int*)(ws + 189400128);            // 800000
    int* blksum = (int*)(ws + 192600128);            // 64
    ushort_t* wt = (ushort_t*)(ws + 192600512);
    ushort_t* w1r_t = wt;                 // 256x96   @0
    ushort_t* w1o_t = wt + 24576;         // 256x96
    ushort_t* w2r_t = wt + 49152;         // 512x256
    ushort_t* w2o_t = wt + 180224;        // 512x256
    ushort_t* w3r_t = wt + 311296;        // 512x512
    ushort_t* w3o_t = wt + 573440;        // 512x512
    ushort_t* wfc_t = wt + 835584;        // 128x512

    float* x_atom = (float*)d_out;
    float* pooled = x_atom + (size_t)N_NODES * OUT_DIM;

    const int* src = ei;
    const int* dst = ei + N_EDGES;

    // ---- conversions: all weights in ONE launch; x pad+cast ----
    wt_all_kernel<<<(901120 + 255) / 256, 256, 0, stream>>>(W1r, W1o, W2r, W2o,
                                                            W3r, W3o, Wfc, wt);
    pad_cast_kernel<<<((N_NODES * K1P) + 255) / 256, 256, 0, stream>>>(x, xb, N_NODES, IN_DIM, K1P);

    // ---- CSR build ----
    hipMemsetAsync(deg, 0, N_NODES * sizeof(int), stream);
    hist_kernel<<<(N_EDGES + 255) / 256, 256, 0, stream>>>(dst, deg, N_EDGES);
    {
        int nb = (N_NODES + 1023) / 1024;   // 49
        scan1_kernel<<<nb, 1024, 0, stream>>>(deg, rowptr, blksum, N_NODES);
        scan2_kernel<<<1, 64, 0, stream>>>(blksum, nb);
        scan3_kernel<<<(N_NODES + 1 + 255) / 256, 256, 0, stream>>>(blksum, rowptr, cursor, N_NODES);
    }
    fill_kernel<<<(N_EDGES + 255) / 256, 256, 0, stream>>>(src, dst, cursor, csrsrc, N_EDGES);

    const int GY = (N_NODES + 127) / 128;   // 391
    const int AGG_BLKS = (N_NODES + 3) / 4;

    // ---- layer 1: 78(pad96) -> 256 ----
    csr_agg_wave_kernel<2><<<AGG_BLKS, 256, 0, stream>>>(xb, rowptr, csrsrc, aggr, K1P);
    mfma_gemm_kernel<<<(HID / 128) * GY, 256, 0, stream>>>(aggr, xb, w1r_t, w1o_t, b1, h1,
                                                           N_NODES, K1P, HID, 1);
    // ---- layer 2: 256 -> 512 ----
    csr_agg_wave_kernel<4><<<AGG_BLKS, 256, 0, stream>>>(h1, rowptr, csrsrc, aggr, HID);
    mfma_gemm_kernel<<<((2 * HID) / 128) * GY, 256, 0, stream>>>(aggr, h1, w2r_t, w2o_t, b2, h2,
                                                                 N_NODES, HID, 2 * HID, 1);
    // ---- layer 3: 512 -> 512 ----
    csr_agg_wave_kernel<8><<<AGG_BLKS, 256, 0, stream>>>(h2, rowptr, csrsrc, aggr, 2 * HID);
    mfma_gemm_kernel<<<((2 * HID) / 128) * GY, 256, 0, stream>>>(aggr, h2, w3r_t, w3o_t, b3, h3,
                                                                 N_NODES, 2 * HID, 2 * HID, 1);
    // ---- fc 512->128 fused with LN + ReLU + pool ----
    hipMemsetAsync(pooled, 0, (size_t)N_GRAPHS * OUT_DIM * sizeof(float), stream);
    mfma_fc_ln_kernel<<<GY, 256, 0, stream>>>(h3, wfc_t, bfc, lng, lnb, batch,
                                              x_atom, pooled, N_NODES, 2 * HID);
}

// Round 5
// 630.353 us; speedup vs baseline: 1.2402x; 1.2402x over previous
//
#include <hip/hip_runtime.h>

#define N_NODES 50000
#define N_EDGES 800000
#define N_GRAPHS 1024
#define IN_DIM 78
#define K1P 96            // IN_DIM padded to multiple of 32
#define HID 256
#define OUT_DIM 128

typedef unsigned short ushort_t;
typedef __attribute__((ext_vector_type(8))) short v8s;
typedef __attribute__((ext_vector_type(4))) float v4f;
typedef __attribute__((ext_vector_type(4))) unsigned int u4;
typedef __attribute__((ext_vector_type(2))) unsigned short us2;
typedef __attribute__((ext_vector_type(4))) unsigned short us4;
typedef __attribute__((ext_vector_type(8))) unsigned short us8;

__device__ __forceinline__ ushort_t f2bf(float f) {
    unsigned u = __float_as_uint(f);
    unsigned r = (u + 0x7fffu + ((u >> 16) & 1u)) >> 16;   // RNE
    return (ushort_t)r;
}
__device__ __forceinline__ float bf2f(ushort_t h) {
    return __uint_as_float((unsigned)h << 16);
}

// async global -> LDS, 16B per lane. LDS dest is wave-uniform base + lane*16.
__device__ __forceinline__ void gload16(const ushort_t* g, ushort_t* l) {
    __builtin_amdgcn_global_load_lds(
        (const __attribute__((address_space(1))) void*)g,
        (__attribute__((address_space(3))) void*)l, 16, 0, 0);
}

// bijective XCD-chunked swizzle (m204): orig%8 = XCD round-robin position.
__device__ __forceinline__ int xcd_swizzle(int orig, int nwg) {
    int q = nwg >> 3, r = nwg & 7;
    int xcd = orig & 7, i = orig >> 3;
    return (xcd < r ? xcd * (q + 1) : r * (q + 1) + (xcd - r) * q) + i;
}

// ------------- fused weight transpose+pad+bf16 for ALL weights (1 launch) ------
__global__ __launch_bounds__(256)
void wt_all_kernel(const float* __restrict__ W1r, const float* __restrict__ W1o,
                   const float* __restrict__ W2r, const float* __restrict__ W2o,
                   const float* __restrict__ W3r, const float* __restrict__ W3o,
                   const float* __restrict__ Wfc, ushort_t* __restrict__ out)
{
    int i = blockIdx.x * 256 + threadIdx.x;
    if (i >= 901120) return;
    const float* W; int K, N, Kp, base;
    if      (i < 24576)  { W = W1r; K = IN_DIM; N = HID;     Kp = 96;  base = 0; }
    else if (i < 49152)  { W = W1o; K = IN_DIM; N = HID;     Kp = 96;  base = 24576; }
    else if (i < 180224) { W = W2r; K = HID;    N = 2 * HID; Kp = 256; base = 49152; }
    else if (i < 311296) { W = W2o; K = HID;    N = 2 * HID; Kp = 256; base = 180224; }
    else if (i < 573440) { W = W3r; K = 2*HID;  N = 2 * HID; Kp = 512; base = 311296; }
    else if (i < 835584) { W = W3o; K = 2*HID;  N = 2 * HID; Kp = 512; base = 573440; }
    else                 { W = Wfc; K = 2*HID;  N = OUT_DIM; Kp = 512; base = 835584; }
    int j = i - base;
    int n = j / Kp, k = j - n * Kp;
    float v = (k < K) ? W[(size_t)k * N + n] : 0.0f;
    out[i] = f2bf(v);
}

// ---------------- pad + cast activations: out[r][k<Kin?]=in, else 0 -----------
__global__ __launch_bounds__(256)
void pad_cast_kernel(const float* __restrict__ in, ushort_t* __restrict__ out,
                     int rows, int Kin, int Kout)
{
    int i = blockIdx.x * 256 + threadIdx.x;
    if (i >= rows * Kout) return;
    int r = i / Kout, k = i - r * Kout;
    out[i] = f2bf(k < Kin ? in[(size_t)r * Kin + k] : 0.0f);
}

// ---------------- CSR build ----------------------------------------------------
__global__ __launch_bounds__(256)
void hist_kernel(const int* __restrict__ dstI, int* __restrict__ deg, int nE)
{
    int e = blockIdx.x * 256 + threadIdx.x;
    if (e < nE) {
        int d = dstI[e];
        if ((unsigned)d < (unsigned)N_NODES) atomicAdd(&deg[d], 1);
    }
}

__global__ __launch_bounds__(1024)
void scan1_kernel(const int* __restrict__ deg, int* __restrict__ rowptr,
                  int* __restrict__ blocksum, int n)
{
    __shared__ int s[1024];
    int b = (int)blockIdx.x, t = (int)threadIdx.x;
    int i = b * 1024 + t;
    int v = (i < n) ? deg[i] : 0;
    s[t] = v;
    __syncthreads();
    for (int off = 1; off < 1024; off <<= 1) {
        int a = (t >= off) ? s[t - off] : 0;
        __syncthreads();
        s[t] += a;
        __syncthreads();
    }
    if (i < n) rowptr[i + 1] = s[t];      // block-local inclusive
    if (t == 1023) blocksum[b] = s[1023];
    if (b == 0 && t == 0) rowptr[0] = 0;
}

__global__ __launch_bounds__(64)
void scan2_kernel(int* __restrict__ blocksum, int nb)   // nb <= 64
{
    int t = (int)threadIdx.x;
    int v = (t < nb) ? blocksum[t] : 0;
    #pragma unroll
    for (int off = 1; off < 64; off <<= 1) {
        int a = __shfl_up(v, off, 64);
        if (t >= off) v += a;
    }
    if (t < nb) blocksum[t] = v;
}

__global__ __launch_bounds__(256)
void scan3_kernel(const int* __restrict__ blocksum, int* __restrict__ rowptr,
                  int* __restrict__ cursor, int n)
{
    int j = blockIdx.x * 256 + threadIdx.x;   // 0..n
    if (j > n) return;
    int v;
    if (j == 0) v = 0;
    else {
        int b = (j - 1) >> 10;
        v = rowptr[j] + (b >= 1 ? blocksum[b - 1] : 0);
    }
    rowptr[j] = v;
    if (j < n) cursor[j] = v;
}

__global__ __launch_bounds__(256)
void fill_kernel(const int* __restrict__ srcI, const int* __restrict__ dstI,
                 int* __restrict__ cursor, int* __restrict__ csr_src, int nE)
{
    int e = blockIdx.x * 256 + threadIdx.x;
    if (e < nE) {
        int d = dstI[e];
        int s = srcI[e];
        if ((unsigned)d < (unsigned)N_NODES && (unsigned)s < (unsigned)N_NODES) {
            int pos = atomicAdd(&cursor[d], 1);
            csr_src[pos] = s;
        }
    }
}

// ---------------- CSR aggregation, wave-per-node, 8-deep load pipeline ----------
template<int VPT> struct VecT;
template<> struct VecT<2> { using T = us2; };
template<> struct VecT<4> { using T = us4; };
template<> struct VecT<8> { using T = us8; };

template<int VPT>
__global__ __launch_bounds__(256)
void csr_agg_wave_kernel(const ushort_t* __restrict__ feat,
                         const int* __restrict__ rowptr,
                         const int* __restrict__ csr_src,
                         ushort_t* __restrict__ out, int Ds)
{
    using T = typename VecT<VPT>::T;
    const int wv   = (int)threadIdx.x >> 6;
    const int node = (int)blockIdx.x * 4 + wv;
    if (node >= N_NODES) return;
    const int lane = (int)threadIdx.x & 63;
    const int off0 = lane * VPT;
    const bool act = off0 < Ds;                    // Ds=96: lanes 48..63 idle
    const int off  = act ? off0 : (Ds - VPT);

    const int e0 = rowptr[node], e1 = rowptr[node + 1];
    float acc[VPT];
    #pragma unroll
    for (int i = 0; i < VPT; ++i) acc[i] = 0.0f;

    int e = e0;
    for (; e + 8 <= e1; e += 8) {
        T r[8];
        #pragma unroll
        for (int u = 0; u < 8; ++u) {
            int s = csr_src[e + u];
            r[u] = *(const T*)(feat + (size_t)s * Ds + off);
        }
        #pragma unroll
        for (int u = 0; u < 8; ++u)
            #pragma unroll
            for (int i = 0; i < VPT; ++i) acc[i] += bf2f(r[u][i]);
    }
    for (; e + 4 <= e1; e += 4) {
        T r[4];
        #pragma unroll
        for (int u = 0; u < 4; ++u) {
            int s = csr_src[e + u];
            r[u] = *(const T*)(feat + (size_t)s * Ds + off);
        }
        #pragma unroll
        for (int u = 0; u < 4; ++u)
            #pragma unroll
            for (int i = 0; i < VPT; ++i) acc[i] += bf2f(r[u][i]);
    }
    for (; e < e1; ++e) {
        int s = csr_src[e];
        T r = *(const T*)(feat + (size_t)s * Ds + off);
        #pragma unroll
        for (int i = 0; i < VPT; ++i) acc[i] += bf2f(r[i]);
    }

    if (act) {
        T o;
        #pragma unroll
        for (int i = 0; i < VPT; ++i) o[i] = f2bf(acc[i]);
        *(T*)(out + (size_t)node * Ds + off0) = o;
    }
}

// ---------------- bf16 MFMA GEMM: m97 structure + counted-vmcnt pipeline --------
// out = relu?( A1@W1t^T + A2@W2t^T + bias ),  A*: bf16 [M][K], W*t: bf16 [Fo][K]
// 128x128 tile, BK=32, 4 waves 2x2. global_load_lds(16B) staging into THREE
// 16KB LDS buffers, prefetch distance 2. Per step: s_waitcnt vmcnt(4) waits only
// for the 2-steps-old stage (each wave issues exactly 4 gloads/stage), then raw
// s_barrier (no vmcnt(0) drain -> younger prefetches stay in flight, T4).
// Safety: every wave waits its own stage(i) loads pre-barrier => buf[i] fully
// landed collectively; buf[(i+2)%3]'s prior readers consumed their ds_reads
// (lgkm scoreboard before MFMA) before reaching barrier i.
// bf16 out via LDS re-stage (full 16B/lane stores). K mult of 32, Fo mult of 128.
__global__ __launch_bounds__(256, 3)
void mfma_gemm_kernel(const ushort_t* __restrict__ A1,
                      const ushort_t* __restrict__ A2,
                      const ushort_t* __restrict__ W1t,
                      const ushort_t* __restrict__ W2t,
                      const float* __restrict__ bias,
                      ushort_t* __restrict__ outp,
                      int M, int K, int Fo, int relu)
{
    __shared__ __align__(16) ushort_t smem[24576];   // 3x16KB stage / 34816B epi
    const int tid = (int)threadIdx.x;
    const int l   = tid & 63;
    const int w   = tid >> 6;
    const int q   = l >> 4;
    const int r15 = l & 15;
    const int wm  = w >> 1, wn = w & 1;

    const int wg = xcd_swizzle((int)blockIdx.x, (int)gridDim.x);
    const int nx = Fo >> 7;
    const int bx = wg % nx;
    const int by = wg / nx;
    const int bm = by * 128;
    const int bn = bx * 128;

    const int s1 = K >> 5;                       // steps per pass
    const int nsteps = A2 ? (2 * s1) : s1;       // >= 6 for all our shapes

    // per-lane source offsets for the 2 A-tiles / 2 B-tiles this wave stages
    int aOff[2], bOff[2];
    #pragma unroll
    for (int ii = 0; ii < 2; ++ii) {
        int ar = bm + (w * 2 + ii) * 16 + r15;
        if (ar >= M) ar = M - 1;                 // clamp; rows >= M never stored
        aOff[ii] = ar * K;
        int bc = bn + (w * 2 + ii) * 16 + r15;   // Fo multiple of 128 => in range
        bOff[ii] = bc * K;
    }
    const int kq = q * 8;

    auto stage = [&](int step, int buf) {        // 4 gloads per wave per stage
        const ushort_t* A  = (step >= s1) ? A2  : A1;
        const ushort_t* Bt = (step >= s1) ? W2t : W1t;
        const int k0 = (((step >= s1) ? (step - s1) : step) << 5) + kq;
        ushort_t* db = smem + buf * 8192;
        #pragma unroll
        for (int ii = 0; ii < 2; ++ii)
            gload16(A + aOff[ii] + k0, db + (size_t)(w * 2 + ii) * 512);
        #pragma unroll
        for (int ii = 0; ii < 2; ++ii)
            gload16(Bt + bOff[ii] + k0, db + (size_t)(8 + w * 2 + ii) * 512);
    };

    v4f acc[4][4];
    #pragma unroll
    for (int mt = 0; mt < 4; ++mt)
        #pragma unroll
        for (int nt = 0; nt < 4; ++nt)
            acc[mt][nt] = (v4f){0.0f, 0.0f, 0.0f, 0.0f};

    stage(0, 0);
    stage(1, 1);                                 // 8 loads in flight / wave
    for (int step = 0; step < nsteps; ++step) {
        // wait ONLY the oldest stage (4 loads); keep prefetches in flight
        if (step + 1 < nsteps) { asm volatile("s_waitcnt vmcnt(4)" ::: "memory"); }
        else                   { asm volatile("s_waitcnt vmcnt(0)" ::: "memory"); }
        __builtin_amdgcn_s_barrier();            // raw barrier: NO vmcnt(0) drain
        __builtin_amdgcn_sched_barrier(0);
        if (step + 2 < nsteps) stage(step + 2, (step + 2) % 3);
        const ushort_t* db = smem + (step % 3) * 8192;
        v8s af[4], bf[4];
        #pragma unroll
        for (int mt = 0; mt < 4; ++mt)
            af[mt] = *(const v8s*)(db + (size_t)(wm * 4 + mt) * 512 + l * 8);
        #pragma unroll
        for (int nt = 0; nt < 4; ++nt)
            bf[nt] = *(const v8s*)(db + (size_t)(8 + wn * 4 + nt) * 512 + l * 8);
        #pragma unroll
        for (int mt = 0; mt < 4; ++mt)
            #pragma unroll
            for (int nt = 0; nt < 4; ++nt)
                acc[mt][nt] = __builtin_amdgcn_mfma_f32_16x16x32_bf16(
                    af[mt], bf[nt], acc[mt][nt], 0, 0, 0);
    }

    // epilogue: C/D map col=lane&15, row=q*4+reg; LDS re-stage, 16B/lane stores
    __syncthreads();               // all frag reads done before smem reuse
    #pragma unroll
    for (int nt = 0; nt < 4; ++nt) {
        int col = wn * 64 + nt * 16 + r15;
        float bb = bias[bn + col];
        #pragma unroll
        for (int mt = 0; mt < 4; ++mt) {
            int row0 = wm * 64 + mt * 16 + q * 4;
            #pragma unroll
            for (int p = 0; p < 4; ++p) {
                float v = acc[mt][nt][p] + bb;
                if (relu) v = fmaxf(v, 0.0f);
                smem[(size_t)(row0 + p) * 136 + col] = f2bf(v);
            }
        }
    }
    __syncthreads();
    #pragma unroll
    for (int pass = 0; pass < 8; ++pass) {
        int row = pass * 16 + (tid >> 4);
        int gr  = bm + row;
        if (gr < M) {
            u4 v = *(const u4*)(smem + (size_t)row * 136 + (tid & 15) * 8);
            *(u4*)(outp + (size_t)gr * Fo + bn + (tid & 15) * 8) = v;
        }
    }
}

// ---------------- fc GEMM (Fo=128) + fused LayerNorm + ReLU + pool --------------
// (proven 635us version) Each block owns 128 complete output rows; LN is local.
// Pooling: block-local segmented reduction over sorted batch runs in LDS, then
// ONE atomicAdd per (graph-run x column) with 128 distinct addresses per flush.
__global__ __launch_bounds__(256, 3)
void mfma_fc_ln_kernel(const ushort_t* __restrict__ A,
                       const ushort_t* __restrict__ Wt,
                       const float* __restrict__ bias,
                       const float* __restrict__ gamma,
                       const float* __restrict__ beta,
                       const int* __restrict__ batch,
                       float* __restrict__ x_atom,
                       float* __restrict__ pooled,
                       int M, int K)
{
    __shared__ __align__(16) char smem_raw[34816];   // 32KB dbuf / 64x132 f32
    ushort_t* smem = (ushort_t*)smem_raw;
    float*    sf   = (float*)smem_raw;
    const int tid = (int)threadIdx.x;
    const int l   = tid & 63;
    const int w   = tid >> 6;
    const int q   = l >> 4;
    const int r15 = l & 15;
    const int wm  = w >> 1, wn = w & 1;
    const int bm  = (int)blockIdx.x * 128;
    const int nsteps = K >> 5;

    int aOff[2], bOff[2];
    #pragma unroll
    for (int ii = 0; ii < 2; ++ii) {
        int ar = bm + (w * 2 + ii) * 16 + r15;
        if (ar >= M) ar = M - 1;
        aOff[ii] = ar * K;
        bOff[ii] = ((w * 2 + ii) * 16 + r15) * K;   // Fo=128 cols exactly
    }
    const int kq = q * 8;

    auto stage = [&](int step, int buf) {
        const int k0 = (step << 5) + kq;
        ushort_t* db = smem + buf * 8192;
        #pragma unroll
        for (int ii = 0; ii < 2; ++ii)
            gload16(A + aOff[ii] + k0, db + (size_t)(w * 2 + ii) * 512);
        #pragma unroll
        for (int ii = 0; ii < 2; ++ii)
            gload16(Wt + bOff[ii] + k0, db + (size_t)(8 + w * 2 + ii) * 512);
    };

    v4f acc[4][4];
    #pragma unroll
    for (int mt = 0; mt < 4; ++mt)
        #pragma unroll
        for (int nt = 0; nt < 4; ++nt)
            acc[mt][nt] = (v4f){0.0f, 0.0f, 0.0f, 0.0f};

    stage(0, 0);
    for (int step = 0; step < nsteps; ++step) {
        const int cur = step & 1;
        __syncthreads();
        if (step + 1 < nsteps) stage(step + 1, cur ^ 1);
        const ushort_t* db = smem + cur * 8192;
        v8s af[4], bf[4];
        #pragma unroll
        for (int mt = 0; mt < 4; ++mt)
            af[mt] = *(const v8s*)(db + (size_t)(wm * 4 + mt) * 512 + l * 8);
        #pragma unroll
        for (int nt = 0; nt < 4; ++nt)
            bf[nt] = *(const v8s*)(db + (size_t)(8 + wn * 4 + nt) * 512 + l * 8);
        #pragma unroll
        for (int mt = 0; mt < 4; ++mt)
            #pragma unroll
            for (int nt = 0; nt < 4; ++nt)
                acc[mt][nt] = __builtin_amdgcn_mfma_f32_16x16x32_bf16(
                    af[mt], bf[nt], acc[mt][nt], 0, 0, 0);
    }

    // fused LN epilogue: two halves of 64 rows through LDS (64x132 f32)
    const int lrow = tid >> 2;            // 0..63
    const int c0   = (tid & 3) * 32;
    float pacc = 0.0f;                    // per-column running pool sum (tid<128)
    int   pcur = -1;                      // current graph id of the run
    #pragma unroll
    for (int half = 0; half < 2; ++half) {
        __syncthreads();                  // frag/pooling reads done before overwrite
        if (wm == half) {
            #pragma unroll
            for (int nt = 0; nt < 4; ++nt) {
                int col = wn * 64 + nt * 16 + r15;
                float bb = bias[col];
                #pragma unroll
                for (int mt = 0; mt < 4; ++mt) {
                    int row0 = mt * 16 + q * 4;
                    #pragma unroll
                    for (int p = 0; p < 4; ++p)
                        sf[(size_t)(row0 + p) * 132 + col] = acc[mt][nt][p] + bb;
                }
            }
        }
        __syncthreads();
        int gr = bm + half * 64 + lrow;
        float* rowp = sf + (size_t)lrow * 132 + c0;
        float s = 0.0f;
        #pragma unroll
        for (int j = 0; j < 32; j += 4) {
            v4f t = *(const v4f*)(rowp + j);
            s += t[0] + t[1] + t[2] + t[3];
        }
        s += __shfl_xor(s, 1, 64);
        s += __shfl_xor(s, 2, 64);
        float mean = s * (1.0f / 128.0f);
        float s2 = 0.0f;
        #pragma unroll
        for (int j = 0; j < 32; j += 4) {
            v4f t = *(const v4f*)(rowp + j);
            #pragma unroll
            for (int k = 0; k < 4; ++k) { float d = t[k] - mean; s2 += d * d; }
        }
        s2 += __shfl_xor(s2, 1, 64);
        s2 += __shfl_xor(s2, 2, 64);
        float rstd = rsqrtf(s2 * (1.0f / 128.0f) + 1e-5f);
        bool rok = gr < M;
        #pragma unroll
        for (int j = 0; j < 32; j += 4) {
            v4f t  = *(const v4f*)(rowp + j);
            v4f g  = *(const v4f*)(gamma + c0 + j);
            v4f bt = *(const v4f*)(beta + c0 + j);
            v4f y;
            #pragma unroll
            for (int k = 0; k < 4; ++k)
                y[k] = fmaxf((t[k] - mean) * rstd * g[k] + bt[k], 0.0f);
            if (rok) *(v4f*)(x_atom + (size_t)gr * 128 + c0 + j) = y;
            *(v4f*)(rowp + j) = y;        // y back into LDS for pooling
        }
        __syncthreads();                  // y visible to pooling readers
        if (tid < 128) {                  // thread t owns column t
            for (int r = 0; r < 64; ++r) {
                int grr = bm + half * 64 + r;
                if (grr >= M) break;
                int b = batch[grr];
                if (b != pcur) {
                    if (pcur >= 0 && pacc != 0.0f)
                        atomicAdd(pooled + (size_t)pcur * 128 + tid, pacc);
                    pcur = b; pacc = 0.0f;
                }
                pacc += sf[(size_t)r * 132 + tid];
            }
        }
    }
    if (tid < 128 && pcur >= 0)
        atomicAdd(pooled + (size_t)pcur * 128 + tid, pacc);
}

extern "C" void kernel_launch(void* const* d_in, const int* in_sizes, int n_in,
                              void* d_out, int out_size, void* d_ws, size_t ws_size,
                              hipStream_t stream)
{
    const float* x     = (const float*)d_in[0];
    const int*   ei    = (const int*)d_in[1];
    const int*   batch = (const int*)d_in[2];
    const float* W1r   = (const float*)d_in[3];
    const float* b1    = (const float*)d_in[4];
    const float* W1o   = (const float*)d_in[5];
    const float* W2r   = (const float*)d_in[6];
    const float* b2    = (const float*)d_in[7];
    const float* W2o   = (const float*)d_in[8];
    const float* W3r   = (const float*)d_in[9];
    const float* b3    = (const float*)d_in[10];
    const float* W3o   = (const float*)d_in[11];
    const float* Wfc   = (const float*)d_in[12];
    const float* bfc   = (const float*)d_in[13];
    const float* lng   = (const float*)d_in[14];
    const float* lnb   = (const float*)d_in[15];

    const size_t WS_NEED = 204800000;
    if (ws_size < WS_NEED) {
        hipMemsetAsync(d_out, 0, (size_t)out_size * sizeof(float), stream);
        return;
    }

    char* ws = (char*)d_ws;
    ushort_t* xb   = (ushort_t*)(ws + 0);            // 50000x96 bf16
    ushort_t* h1   = (ushort_t*)(ws + 9600000);      // 50000x256 bf16
    ushort_t* aggr = (ushort_t*)(ws + 35200000);     // up to 50000x512 bf16
    ushort_t* h2   = (ushort_t*)(ws + 86400000);     // 50000x512 bf16
    ushort_t* h3   = (ushort_t*)(ws + 137600000);    // 50000x512 bf16
    int* deg    = (int*)(ws + 188800000);            // 50000
    int* rowptr = (int*)(ws + 189000000);            // 50001
    int* cursor = (int*)(ws + 189200128);            // 50000
    int* csrsrc = (int*)(ws + 189400128);            // 800000
    int* blksum = (int*)(ws + 192600128);            // 64
    ushort_t* wt = (ushort_t*)(ws + 192600512);
    ushort_t* w1r_t = wt;                 // 256x96   @0
    ushort_t* w1o_t = wt + 24576;         // 256x96
    ushort_t* w2r_t = wt + 49152;         // 512x256
    ushort_t* w2o_t = wt + 180224;        // 512x256
    ushort_t* w3r_t = wt + 311296;        // 512x512
    ushort_t* w3o_t = wt + 573440;        // 512x512
    ushort_t* wfc_t = wt + 835584;        // 128x512

    float* x_atom = (float*)d_out;
    float* pooled = x_atom + (size_t)N_NODES * OUT_DIM;

    const int* src = ei;
    const int* dst = ei + N_EDGES;

    // ---- conversions: all weights in ONE launch; x pad+cast ----
    wt_all_kernel<<<(901120 + 255) / 256, 256, 0, stream>>>(W1r, W1o, W2r, W2o,
                                                            W3r, W3o, Wfc, wt);
    pad_cast_kernel<<<((N_NODES * K1P) + 255) / 256, 256, 0, stream>>>(x, xb, N_NODES, IN_DIM, K1P);

    // ---- CSR build ----
    hipMemsetAsync(deg, 0, N_NODES * sizeof(int), stream);
    hist_kernel<<<(N_EDGES + 255) / 256, 256, 0, stream>>>(dst, deg, N_EDGES);
    {
        int nb = (N_NODES + 1023) / 1024;   // 49
        scan1_kernel<<<nb, 1024, 0, stream>>>(deg, rowptr, blksum, N_NODES);
        scan2_kernel<<<1, 64, 0, stream>>>(blksum, nb);
        scan3_kernel<<<(N_NODES + 1 + 255) / 256, 256, 0, stream>>>(blksum, rowptr, cursor, N_NODES);
    }
    fill_kernel<<<(N_EDGES + 255) / 256, 256, 0, stream>>>(src, dst, cursor, csrsrc, N_EDGES);

    const int GY = (N_NODES + 127) / 128;   // 391
    const int AGG_BLKS = (N_NODES + 3) / 4;

    // ---- layer 1: 78(pad96) -> 256 ----
    csr_agg_wave_kernel<2><<<AGG_BLKS, 256, 0, stream>>>(xb, rowptr, csrsrc, aggr, K1P);
    mfma_gemm_kernel<<<(HID / 128) * GY, 256, 0, stream>>>(aggr, xb, w1r_t, w1o_t, b1, h1,
                                                           N_NODES, K1P, HID, 1);
    // ---- layer 2: 256 -> 512 ----
    csr_agg_wave_kernel<4><<<AGG_BLKS, 256, 0, stream>>>(h1, rowptr, csrsrc, aggr, HID);
    mfma_gemm_kernel<<<((2 * HID) / 128) * GY, 256, 0, stream>>>(aggr, h1, w2r_t, w2o_t, b2, h2,
                                                                 N_NODES, HID, 2 * HID, 1);
    // ---- layer 3: 512 -> 512 ----
    csr_agg_wave_kernel<8><<<AGG_BLKS, 256, 0, stream>>>(h2, rowptr, csrsrc, aggr, 2 * HID);
    mfma_gemm_kernel<<<((2 * HID) / 128) * GY, 256, 0, stream>>>(aggr, h2, w3r_t, w3o_t, b3, h3,
                                                                 N_NODES, 2 * HID, 2 * HID, 1);
    // ---- fc 512->128 fused with LN + ReLU + pool ----
    hipMemsetAsync(pooled, 0, (size_t)N_GRAPHS * OUT_DIM * sizeof(float), stream);
    mfma_fc_ln_kernel<<<GY, 256, 0, stream>>>(h3, wfc_t, bfc, lng, lnb, batch,
                                              x_atom, pooled, N_NODES, 2 * HID);
}

// Round 6
// 605.253 us; speedup vs baseline: 1.2916x; 1.0415x over previous
//
#include <hip/hip_runtime.h>

#define N_NODES 50000
#define N_EDGES 800000
#define N_GRAPHS 1024
#define IN_DIM 78
#define K1P 96            // IN_DIM padded to multiple of 32
#define HID 256
#define OUT_DIM 128

typedef unsigned short ushort_t;
typedef __attribute__((ext_vector_type(8))) short v8s;
typedef __attribute__((ext_vector_type(4))) float v4f;
typedef __attribute__((ext_vector_type(4))) unsigned int u4;
typedef __attribute__((ext_vector_type(2))) unsigned short us2;
typedef __attribute__((ext_vector_type(4))) unsigned short us4;
typedef __attribute__((ext_vector_type(8))) unsigned short us8;

__device__ __forceinline__ ushort_t f2bf(float f) {
    unsigned u = __float_as_uint(f);
    unsigned r = (u + 0x7fffu + ((u >> 16) & 1u)) >> 16;   // RNE
    return (ushort_t)r;
}
__device__ __forceinline__ float bf2f(ushort_t h) {
    return __uint_as_float((unsigned)h << 16);
}

// async global -> LDS, 16B per lane. LDS dest is wave-uniform base + lane*16.
__device__ __forceinline__ void gload16(const ushort_t* g, ushort_t* l) {
    __builtin_amdgcn_global_load_lds(
        (const __attribute__((address_space(1))) void*)g,
        (__attribute__((address_space(3))) void*)l, 16, 0, 0);
}

// bijective XCD-chunked swizzle (m204): orig%8 = XCD round-robin position.
__device__ __forceinline__ int xcd_swizzle(int orig, int nwg) {
    int q = nwg >> 3, r = nwg & 7;
    int xcd = orig & 7, i = orig >> 3;
    return (xcd < r ? xcd * (q + 1) : r * (q + 1) + (xcd - r) * q) + i;
}

// ------------- fused weight transpose+pad+bf16 for ALL weights (1 launch) ------
__global__ __launch_bounds__(256)
void wt_all_kernel(const float* __restrict__ W1r, const float* __restrict__ W1o,
                   const float* __restrict__ W2r, const float* __restrict__ W2o,
                   const float* __restrict__ W3r, const float* __restrict__ W3o,
                   const float* __restrict__ Wfc, ushort_t* __restrict__ out)
{
    int i = blockIdx.x * 256 + threadIdx.x;
    if (i >= 901120) return;
    const float* W; int K, N, Kp, base;
    if      (i < 24576)  { W = W1r; K = IN_DIM; N = HID;     Kp = 96;  base = 0; }
    else if (i < 49152)  { W = W1o; K = IN_DIM; N = HID;     Kp = 96;  base = 24576; }
    else if (i < 180224) { W = W2r; K = HID;    N = 2 * HID; Kp = 256; base = 49152; }
    else if (i < 311296) { W = W2o; K = HID;    N = 2 * HID; Kp = 256; base = 180224; }
    else if (i < 573440) { W = W3r; K = 2*HID;  N = 2 * HID; Kp = 512; base = 311296; }
    else if (i < 835584) { W = W3o; K = 2*HID;  N = 2 * HID; Kp = 512; base = 573440; }
    else                 { W = Wfc; K = 2*HID;  N = OUT_DIM; Kp = 512; base = 835584; }
    int j = i - base;
    int n = j / Kp, k = j - n * Kp;
    float v = (k < K) ? W[(size_t)k * N + n] : 0.0f;
    out[i] = f2bf(v);
}

// ---------------- pad + cast activations: out[r][k<Kin?]=in, else 0 -----------
__global__ __launch_bounds__(256)
void pad_cast_kernel(const float* __restrict__ in, ushort_t* __restrict__ out,
                     int rows, int Kin, int Kout)
{
    int i = blockIdx.x * 256 + threadIdx.x;
    if (i >= rows * Kout) return;
    int r = i / Kout, k = i - r * Kout;
    out[i] = f2bf(k < Kin ? in[(size_t)r * Kin + k] : 0.0f);
}

// ---------------- CSR build ----------------------------------------------------
__global__ __launch_bounds__(256)
void hist_kernel(const int* __restrict__ dstI, int* __restrict__ deg, int nE)
{
    int e = blockIdx.x * 256 + threadIdx.x;
    if (e < nE) {
        int d = dstI[e];
        if ((unsigned)d < (unsigned)N_NODES) atomicAdd(&deg[d], 1);
    }
}

__global__ __launch_bounds__(1024)
void scan1_kernel(const int* __restrict__ deg, int* __restrict__ rowptr,
                  int* __restrict__ blocksum, int n)
{
    __shared__ int s[1024];
    int b = (int)blockIdx.x, t = (int)threadIdx.x;
    int i = b * 1024 + t;
    int v = (i < n) ? deg[i] : 0;
    s[t] = v;
    __syncthreads();
    for (int off = 1; off < 1024; off <<= 1) {
        int a = (t >= off) ? s[t - off] : 0;
        __syncthreads();
        s[t] += a;
        __syncthreads();
    }
    if (i < n) rowptr[i + 1] = s[t];      // block-local inclusive
    if (t == 1023) blocksum[b] = s[1023];
    if (b == 0 && t == 0) rowptr[0] = 0;
}

__global__ __launch_bounds__(64)
void scan2_kernel(int* __restrict__ blocksum, int nb)   // nb <= 64
{
    int t = (int)threadIdx.x;
    int v = (t < nb) ? blocksum[t] : 0;
    #pragma unroll
    for (int off = 1; off < 64; off <<= 1) {
        int a = __shfl_up(v, off, 64);
        if (t >= off) v += a;
    }
    if (t < nb) blocksum[t] = v;
}

__global__ __launch_bounds__(256)
void scan3_kernel(const int* __restrict__ blocksum, int* __restrict__ rowptr,
                  int* __restrict__ cursor, int n)
{
    int j = blockIdx.x * 256 + threadIdx.x;   // 0..n
    if (j > n) return;
    int v;
    if (j == 0) v = 0;
    else {
        int b = (j - 1) >> 10;
        v = rowptr[j] + (b >= 1 ? blocksum[b - 1] : 0);
    }
    rowptr[j] = v;
    if (j < n) cursor[j] = v;
}

__global__ __launch_bounds__(256)
void fill_kernel(const int* __restrict__ srcI, const int* __restrict__ dstI,
                 int* __restrict__ cursor, int* __restrict__ csr_src, int nE)
{
    int e = blockIdx.x * 256 + threadIdx.x;
    if (e < nE) {
        int d = dstI[e];
        int s = srcI[e];
        if ((unsigned)d < (unsigned)N_NODES && (unsigned)s < (unsigned)N_NODES) {
            int pos = atomicAdd(&cursor[d], 1);
            csr_src[pos] = s;
        }
    }
}

// ---------------- CSR aggregation, wave-per-node, 8-deep load pipeline ----------
template<int VPT> struct VecT;
template<> struct VecT<2> { using T = us2; };
template<> struct VecT<4> { using T = us4; };
template<> struct VecT<8> { using T = us8; };

template<int VPT>
__global__ __launch_bounds__(256)
void csr_agg_wave_kernel(const ushort_t* __restrict__ feat,
                         const int* __restrict__ rowptr,
                         const int* __restrict__ csr_src,
                         ushort_t* __restrict__ out, int Ds)
{
    using T = typename VecT<VPT>::T;
    const int wv   = (int)threadIdx.x >> 6;
    const int node = (int)blockIdx.x * 4 + wv;
    if (node >= N_NODES) return;
    const int lane = (int)threadIdx.x & 63;
    const int off0 = lane * VPT;
    const bool act = off0 < Ds;                    // Ds=96: lanes 48..63 idle
    const int off  = act ? off0 : (Ds - VPT);

    const int e0 = rowptr[node], e1 = rowptr[node + 1];
    float acc[VPT];
    #pragma unroll
    for (int i = 0; i < VPT; ++i) acc[i] = 0.0f;

    int e = e0;
    for (; e + 8 <= e1; e += 8) {
        T r[8];
        #pragma unroll
        for (int u = 0; u < 8; ++u) {
            int s = csr_src[e + u];
            r[u] = *(const T*)(feat + (size_t)s * Ds + off);
        }
        #pragma unroll
        for (int u = 0; u < 8; ++u)
            #pragma unroll
            for (int i = 0; i < VPT; ++i) acc[i] += bf2f(r[u][i]);
    }
    for (; e + 4 <= e1; e += 4) {
        T r[4];
        #pragma unroll
        for (int u = 0; u < 4; ++u) {
            int s = csr_src[e + u];
            r[u] = *(const T*)(feat + (size_t)s * Ds + off);
        }
        #pragma unroll
        for (int u = 0; u < 4; ++u)
            #pragma unroll
            for (int i = 0; i < VPT; ++i) acc[i] += bf2f(r[u][i]);
    }
    for (; e < e1; ++e) {
        int s = csr_src[e];
        T r = *(const T*)(feat + (size_t)s * Ds + off);
        #pragma unroll
        for (int i = 0; i < VPT; ++i) acc[i] += bf2f(r[i]);
    }

    if (act) {
        T o;
        #pragma unroll
        for (int i = 0; i < VPT; ++i) o[i] = f2bf(acc[i]);
        *(T*)(out + (size_t)node * Ds + off0) = o;
    }
}

// ---------------- bf16 MFMA GEMM: 256x256 tile, 8 waves, 3-buffer pipeline ------
// out = relu?( A1@W1t^T + A2@W2t^T + bias ),  A*: bf16 [M][K], W*t: bf16 [Fo][K]
// BK=32. 8 waves (2M x 4N); wave owns 128x64 => acc[8][4]. LDS: 3 x 32KB K-tile
// buffers (A 16 m-tiles + B 16 n-tiles of 1KB, lane-ordered). Per tile u:
//   s_waitcnt vmcnt(8)   -- tile u's 4 stage loads landed; u+1,u+2 in flight
//   s_barrier            -- collective: buf[u%3] fully staged
//   32 MFMA/wave (2 phases of af[4]+bf[4] / af[4] reads)
//   s_barrier            -- all reads of buf[u%3] done
//   stage(u+3) -> buf[(u+3)%3] (= buf[u%3], just freed)   [4 gloads/thread]
// Counted waits, never vmcnt(0) mid-loop; ~2-tile lookahead hides L2/HBM latency.
// Requires: K mult of 32, Fo mult of 256. M-tail: A rows clamped (never stored).
__global__ __launch_bounds__(512, 2)
void mfma_gemm256_kernel(const ushort_t* __restrict__ A1,
                         const ushort_t* __restrict__ A2,
                         const ushort_t* __restrict__ W1t,
                         const ushort_t* __restrict__ W2t,
                         const float* __restrict__ bias,
                         ushort_t* __restrict__ outp,
                         int M, int K, int Fo, int relu)
{
    __shared__ __align__(16) ushort_t smem[49152];   // 3 x 32KB; epi reuses 66KB
    const int tid = (int)threadIdx.x;
    const int l   = tid & 63;
    const int w   = tid >> 6;          // 0..7
    const int q   = l >> 4;
    const int r15 = l & 15;
    const int wm  = w >> 2;            // 0..1  (M half)
    const int wn  = w & 3;             // 0..3  (N quarter)

    const int wg = xcd_swizzle((int)blockIdx.x, (int)gridDim.x);
    const int nx = Fo >> 8;            // col panels of 256
    const int bx = wg % nx;
    const int by = wg / nx;
    const int bm = by * 256;
    const int bn = bx * 256;

    const int s1 = K >> 5;
    const int NT = A2 ? (2 * s1) : s1;               // >= 6 for all our shapes

    // per-lane global row/col offsets for the 4 staged subtiles (2 A + 2 B)
    int aOff[2], bOff[2];
    #pragma unroll
    for (int r = 0; r < 2; ++r) {
        int ar = bm + (r * 8 + w) * 16 + r15;        // m-tile r*8+w
        if (ar >= M) ar = M - 1;                     // clamp; rows>=M never stored
        aOff[r] = ar * K;
        int bc = bn + (r * 8 + w) * 16 + r15;        // n-tile r*8+w; Fo mult 256
        bOff[r] = bc * K;
    }
    const int kq = q * 8;

    auto stage = [&](int t) {                        // 4 gloads per thread
        const ushort_t* A  = (t >= s1) ? A2  : A1;
        const ushort_t* Bt = (t >= s1) ? W2t : W1t;
        const int k0 = (((t >= s1) ? (t - s1) : t) << 5) + kq;
        ushort_t* buf = smem + (t % 3) * 16384;
        #pragma unroll
        for (int r = 0; r < 2; ++r)
            gload16(A + aOff[r] + k0, buf + (size_t)(r * 8 + w) * 512);
        #pragma unroll
        for (int r = 0; r < 2; ++r)
            gload16(Bt + bOff[r] + k0, buf + 8192 + (size_t)(r * 8 + w) * 512);
    };

    v4f acc[8][4];
    #pragma unroll
    for (int i = 0; i < 8; ++i)
        #pragma unroll
        for (int j = 0; j < 4; ++j)
            acc[i][j] = (v4f){0.0f, 0.0f, 0.0f, 0.0f};

    stage(0); stage(1); stage(2);                    // 12 loads in flight
    __builtin_amdgcn_sched_barrier(0);

    for (int u = 0; u < NT; ++u) {
        const int young = (NT - 1 - u) >= 2 ? 2 : (NT - 1 - u);
        if (young == 2)      { asm volatile("s_waitcnt vmcnt(8)" ::: "memory"); }
        else if (young == 1) { asm volatile("s_waitcnt vmcnt(4)" ::: "memory"); }
        else                 { asm volatile("s_waitcnt vmcnt(0)" ::: "memory"); }
        __builtin_amdgcn_s_barrier();                // buf[u%3] staged & visible
        __builtin_amdgcn_sched_barrier(0);

        const ushort_t* bufA = smem + (u % 3) * 16384;
        const ushort_t* bufB = bufA + 8192;

        v8s af[4], bf[4];
        // phase 0: m-tiles wm*8+0..3
        #pragma unroll
        for (int i = 0; i < 4; ++i)
            af[i] = *(const v8s*)(bufA + (size_t)(wm * 8 + i) * 512 + l * 8);
        #pragma unroll
        for (int j = 0; j < 4; ++j)
            bf[j] = *(const v8s*)(bufB + (size_t)(wn * 4 + j) * 512 + l * 8);
        #pragma unroll
        for (int i = 0; i < 4; ++i)
            #pragma unroll
            for (int j = 0; j < 4; ++j)
                acc[i][j] = __builtin_amdgcn_mfma_f32_16x16x32_bf16(
                    af[i], bf[j], acc[i][j], 0, 0, 0);
        // phase 1: m-tiles wm*8+4..7 (bf reused)
        #pragma unroll
        for (int i = 0; i < 4; ++i)
            af[i] = *(const v8s*)(bufA + (size_t)(wm * 8 + 4 + i) * 512 + l * 8);
        #pragma unroll
        for (int i = 0; i < 4; ++i)
            #pragma unroll
            for (int j = 0; j < 4; ++j)
                acc[4 + i][j] = __builtin_amdgcn_mfma_f32_16x16x32_bf16(
                    af[i], bf[j], acc[4 + i][j], 0, 0, 0);

        __builtin_amdgcn_sched_barrier(0);
        __builtin_amdgcn_s_barrier();                // all reads of buf[u%3] done
        __builtin_amdgcn_sched_barrier(0);
        if (u + 3 < NT) stage(u + 3);                // overwrite just-freed buf
    }

    // ---- epilogue: two 128-row halves restaged through LDS, 16B/lane stores ----
    // acc[i][j] reg p: row bm + wm*128 + i*16 + q*4 + p, col bn + (wn*4+j)*16+r15
    asm volatile("s_waitcnt vmcnt(0)" ::: "memory");   // quiesce any stray loads
    #pragma unroll
    for (int half = 0; half < 2; ++half) {
        __builtin_amdgcn_s_barrier();                // prev reads of smem done
        __builtin_amdgcn_sched_barrier(0);
        if (wm == half) {
            #pragma unroll
            for (int j = 0; j < 4; ++j) {
                int col = (wn * 4 + j) * 16 + r15;
                float bb = bias[bn + col];
                #pragma unroll
                for (int i = 0; i < 8; ++i) {
                    int row0 = i * 16 + q * 4;
                    #pragma unroll
                    for (int p = 0; p < 4; ++p) {
                        float v = acc[i][j][p] + bb;
                        if (relu) v = fmaxf(v, 0.0f);
                        smem[(size_t)(row0 + p) * 264 + col] = f2bf(v);
                    }
                }
            }
        }
        __builtin_amdgcn_sched_barrier(0);
        __builtin_amdgcn_s_barrier();
        __builtin_amdgcn_sched_barrier(0);
        #pragma unroll
        for (int pass = 0; pass < 8; ++pass) {
            int row = pass * 16 + (tid >> 5);
            int gr  = bm + half * 128 + row;
            if (gr < M) {
                u4 v = *(const u4*)(smem + (size_t)row * 264 + (tid & 31) * 8);
                *(u4*)(outp + (size_t)gr * Fo + bn + (tid & 31) * 8) = v;
            }
        }
    }
}

// ---------------- fc GEMM (Fo=128) + fused LayerNorm + ReLU + pool --------------
// (proven version) Each block owns 128 complete output rows; LN is local.
// Pooling: block-local segmented reduction over sorted batch runs in LDS, then
// ONE atomicAdd per (graph-run x column) with 128 distinct addresses per flush.
__global__ __launch_bounds__(256, 3)
void mfma_fc_ln_kernel(const ushort_t* __restrict__ A,
                       const ushort_t* __restrict__ Wt,
                       const float* __restrict__ bias,
                       const float* __restrict__ gamma,
                       const float* __restrict__ beta,
                       const int* __restrict__ batch,
                       float* __restrict__ x_atom,
                       float* __restrict__ pooled,
                       int M, int K)
{
    __shared__ __align__(16) char smem_raw[34816];   // 32KB dbuf / 64x132 f32
    ushort_t* smem = (ushort_t*)smem_raw;
    float*    sf   = (float*)smem_raw;
    const int tid = (int)threadIdx.x;
    const int l   = tid & 63;
    const int w   = tid >> 6;
    const int q   = l >> 4;
    const int r15 = l & 15;
    const int wm  = w >> 1, wn = w & 1;
    const int bm  = (int)blockIdx.x * 128;
    const int nsteps = K >> 5;

    int aOff[2], bOff[2];
    #pragma unroll
    for (int ii = 0; ii < 2; ++ii) {
        int ar = bm + (w * 2 + ii) * 16 + r15;
        if (ar >= M) ar = M - 1;
        aOff[ii] = ar * K;
        bOff[ii] = ((w * 2 + ii) * 16 + r15) * K;   // Fo=128 cols exactly
    }
    const int kq = q * 8;

    auto stage = [&](int step, int buf) {
        const int k0 = (step << 5) + kq;
        ushort_t* db = smem + buf * 8192;
        #pragma unroll
        for (int ii = 0; ii < 2; ++ii)
            gload16(A + aOff[ii] + k0, db + (size_t)(w * 2 + ii) * 512);
        #pragma unroll
        for (int ii = 0; ii < 2; ++ii)
            gload16(Wt + bOff[ii] + k0, db + (size_t)(8 + w * 2 + ii) * 512);
    };

    v4f acc[4][4];
    #pragma unroll
    for (int mt = 0; mt < 4; ++mt)
        #pragma unroll
        for (int nt = 0; nt < 4; ++nt)
            acc[mt][nt] = (v4f){0.0f, 0.0f, 0.0f, 0.0f};

    stage(0, 0);
    for (int step = 0; step < nsteps; ++step) {
        const int cur = step & 1;
        __syncthreads();
        if (step + 1 < nsteps) stage(step + 1, cur ^ 1);
        const ushort_t* db = smem + cur * 8192;
        v8s af[4], bf[4];
        #pragma unroll
        for (int mt = 0; mt < 4; ++mt)
            af[mt] = *(const v8s*)(db + (size_t)(wm * 4 + mt) * 512 + l * 8);
        #pragma unroll
        for (int nt = 0; nt < 4; ++nt)
            bf[nt] = *(const v8s*)(db + (size_t)(8 + wn * 4 + nt) * 512 + l * 8);
        #pragma unroll
        for (int mt = 0; mt < 4; ++mt)
            #pragma unroll
            for (int nt = 0; nt < 4; ++nt)
                acc[mt][nt] = __builtin_amdgcn_mfma_f32_16x16x32_bf16(
                    af[mt], bf[nt], acc[mt][nt], 0, 0, 0);
    }

    // fused LN epilogue: two halves of 64 rows through LDS (64x132 f32)
    const int lrow = tid >> 2;            // 0..63
    const int c0   = (tid & 3) * 32;
    float pacc = 0.0f;                    // per-column running pool sum (tid<128)
    int   pcur = -1;                      // current graph id of the run
    #pragma unroll
    for (int half = 0; half < 2; ++half) {
        __syncthreads();                  // frag/pooling reads done before overwrite
        if (wm == half) {
            #pragma unroll
            for (int nt = 0; nt < 4; ++nt) {
                int col = wn * 64 + nt * 16 + r15;
                float bb = bias[col];
                #pragma unroll
                for (int mt = 0; mt < 4; ++mt) {
                    int row0 = mt * 16 + q * 4;
                    #pragma unroll
                    for (int p = 0; p < 4; ++p)
                        sf[(size_t)(row0 + p) * 132 + col] = acc[mt][nt][p] + bb;
                }
            }
        }
        __syncthreads();
        int gr = bm + half * 64 + lrow;
        float* rowp = sf + (size_t)lrow * 132 + c0;
        float s = 0.0f;
        #pragma unroll
        for (int j = 0; j < 32; j += 4) {
            v4f t = *(const v4f*)(rowp + j);
            s += t[0] + t[1] + t[2] + t[3];
        }
        s += __shfl_xor(s, 1, 64);
        s += __shfl_xor(s, 2, 64);
        float mean = s * (1.0f / 128.0f);
        float s2 = 0.0f;
        #pragma unroll
        for (int j = 0; j < 32; j += 4) {
            v4f t = *(const v4f*)(rowp + j);
            #pragma unroll
            for (int k = 0; k < 4; ++k) { float d = t[k] - mean; s2 += d * d; }
        }
        s2 += __shfl_xor(s2, 1, 64);
        s2 += __shfl_xor(s2, 2, 64);
        float rstd = rsqrtf(s2 * (1.0f / 128.0f) + 1e-5f);
        bool rok = gr < M;
        #pragma unroll
        for (int j = 0; j < 32; j += 4) {
            v4f t  = *(const v4f*)(rowp + j);
            v4f g  = *(const v4f*)(gamma + c0 + j);
            v4f bt = *(const v4f*)(beta + c0 + j);
            v4f y;
            #pragma unroll
            for (int k = 0; k < 4; ++k)
                y[k] = fmaxf((t[k] - mean) * rstd * g[k] + bt[k], 0.0f);
            if (rok) *(v4f*)(x_atom + (size_t)gr * 128 + c0 + j) = y;
            *(v4f*)(rowp + j) = y;        // y back into LDS for pooling
        }
        __syncthreads();                  // y visible to pooling readers
        if (tid < 128) {                  // thread t owns column t
            for (int r = 0; r < 64; ++r) {
                int grr = bm + half * 64 + r;
                if (grr >= M) break;
                int b = batch[grr];
                if (b != pcur) {
                    if (pcur >= 0 && pacc != 0.0f)
                        atomicAdd(pooled + (size_t)pcur * 128 + tid, pacc);
                    pcur = b; pacc = 0.0f;
                }
                pacc += sf[(size_t)r * 132 + tid];
            }
        }
    }
    if (tid < 128 && pcur >= 0)
        atomicAdd(pooled + (size_t)pcur * 128 + tid, pacc);
}

extern "C" void kernel_launch(void* const* d_in, const int* in_sizes, int n_in,
                              void* d_out, int out_size, void* d_ws, size_t ws_size,
                              hipStream_t stream)
{
    const float* x     = (const float*)d_in[0];
    const int*   ei    = (const int*)d_in[1];
    const int*   batch = (const int*)d_in[2];
    const float* W1r   = (const float*)d_in[3];
    const float* b1    = (const float*)d_in[4];
    const float* W1o   = (const float*)d_in[5];
    const float* W2r   = (const float*)d_in[6];
    const float* b2    = (const float*)d_in[7];
    const float* W2o   = (const float*)d_in[8];
    const float* W3r   = (const float*)d_in[9];
    const float* b3    = (const float*)d_in[10];
    const float* W3o   = (const float*)d_in[11];
    const float* Wfc   = (const float*)d_in[12];
    const float* bfc   = (const float*)d_in[13];
    const float* lng   = (const float*)d_in[14];
    const float* lnb   = (const float*)d_in[15];

    const size_t WS_NEED = 204800000;
    if (ws_size < WS_NEED) {
        hipMemsetAsync(d_out, 0, (size_t)out_size * sizeof(float), stream);
        return;
    }

    char* ws = (char*)d_ws;
    ushort_t* xb   = (ushort_t*)(ws + 0);            // 50000x96 bf16
    ushort_t* h1   = (ushort_t*)(ws + 9600000);      // 50000x256 bf16
    ushort_t* aggr = (ushort_t*)(ws + 35200000);     // up to 50000x512 bf16
    ushort_t* h2   = (ushort_t*)(ws + 86400000);     // 50000x512 bf16
    ushort_t* h3   = (ushort_t*)(ws + 137600000);    // 50000x512 bf16
    int* deg    = (int*)(ws + 188800000);            // 50000
    int* rowptr = (int*)(ws + 189000000);            // 50001
    int* cursor = (int*)(ws + 189200128);            // 50000
    int* csrsrc = (int*)(ws + 189400128);            // 800000
    int* blksum = (int*)(ws + 192600128);            // 64
    ushort_t* wt = (ushort_t*)(ws + 192600512);
    ushort_t* w1r_t = wt;                 // 256x96   @0
    ushort_t* w1o_t = wt + 24576;         // 256x96
    ushort_t* w2r_t = wt + 49152;         // 512x256
    ushort_t* w2o_t = wt + 180224;        // 512x256
    ushort_t* w3r_t = wt + 311296;        // 512x512
    ushort_t* w3o_t = wt + 573440;        // 512x512
    ushort_t* wfc_t = wt + 835584;        // 128x512

    float* x_atom = (float*)d_out;
    float* pooled = x_atom + (size_t)N_NODES * OUT_DIM;

    const int* src = ei;
    const int* dst = ei + N_EDGES;

    // ---- conversions: all weights in ONE launch; x pad+cast ----
    wt_all_kernel<<<(901120 + 255) / 256, 256, 0, stream>>>(W1r, W1o, W2r, W2o,
                                                            W3r, W3o, Wfc, wt);
    pad_cast_kernel<<<((N_NODES * K1P) + 255) / 256, 256, 0, stream>>>(x, xb, N_NODES, IN_DIM, K1P);

    // ---- CSR build ----
    hipMemsetAsync(deg, 0, N_NODES * sizeof(int), stream);
    hist_kernel<<<(N_EDGES + 255) / 256, 256, 0, stream>>>(dst, deg, N_EDGES);
    {
        int nb = (N_NODES + 1023) / 1024;   // 49
        scan1_kernel<<<nb, 1024, 0, stream>>>(deg, rowptr, blksum, N_NODES);
        scan2_kernel<<<1, 64, 0, stream>>>(blksum, nb);
        scan3_kernel<<<(N_NODES + 1 + 255) / 256, 256, 0, stream>>>(blksum, rowptr, cursor, N_NODES);
    }
    fill_kernel<<<(N_EDGES + 255) / 256, 256, 0, stream>>>(src, dst, cursor, csrsrc, N_EDGES);

    const int GY128 = (N_NODES + 127) / 128;   // 391 (fc)
    const int GY256 = (N_NODES + 255) / 256;   // 196 (gemm tiles)
    const int AGG_BLKS = (N_NODES + 3) / 4;

    // ---- layer 1: 78(pad96) -> 256 ----
    csr_agg_wave_kernel<2><<<AGG_BLKS, 256, 0, stream>>>(xb, rowptr, csrsrc, aggr, K1P);
    mfma_gemm256_kernel<<<(HID / 256) * GY256, 512, 0, stream>>>(aggr, xb, w1r_t, w1o_t, b1, h1,
                                                                 N_NODES, K1P, HID, 1);
    // ---- layer 2: 256 -> 512 ----
    csr_agg_wave_kernel<4><<<AGG_BLKS, 256, 0, stream>>>(h1, rowptr, csrsrc, aggr, HID);
    mfma_gemm256_kernel<<<((2 * HID) / 256) * GY256, 512, 0, stream>>>(aggr, h1, w2r_t, w2o_t, b2, h2,
                                                                       N_NODES, HID, 2 * HID, 1);
    // ---- layer 3: 512 -> 512 ----
    csr_agg_wave_kernel<8><<<AGG_BLKS, 256, 0, stream>>>(h2, rowptr, csrsrc, aggr, 2 * HID);
    mfma_gemm256_kernel<<<((2 * HID) / 256) * GY256, 512, 0, stream>>>(aggr, h2, w3r_t, w3o_t, b3, h3,
                                                                       N_NODES, 2 * HID, 2 * HID, 1);
    // ---- fc 512->128 fused with LN + ReLU + pool ----
    hipMemsetAsync(pooled, 0, (size_t)N_GRAPHS * OUT_DIM * sizeof(float), stream);
    mfma_fc_ln_kernel<<<GY128, 256, 0, stream>>>(h3, wfc_t, bfc, lng, lnb, batch,
                                                 x_atom, pooled, N_NODES, 2 * HID);
}